// Round 7
// baseline (140.240 us; speedup 1.0000x reference)
//
#include <hip/hip_runtime.h>

#define FEAT 256
#define EMB 256

typedef __attribute__((ext_vector_type(4))) float f32x4;
typedef __attribute__((ext_vector_type(8))) short short8;

// packed fp32x2 -> bf16x2 (RNE) in one instruction
__device__ __forceinline__ unsigned cvtpk(float lo, float hi) {
    unsigned r;
    asm volatile("v_cvt_pk_bf16_f32 %0, %1, %2" : "=v"(r) : "v"(lo), "v"(hi));
    return r;
}

// h = X @ W^T quantized to int8 (biased-u8). H layout: row-major 256B rows,
// within-row byte order [blk(4)][cc(16)][j(4)] so dword (blk*16+cc) holds the
// 4 j-values (cols blk*64 + j*16 + cc) of MFMA lane cc -> single dword store.
// S[row][blk] = per-(row, 64-col block) dequant scale (wave-local absmax).
// 256-row tile, 1024 threads, 16 waves in 4x4 (wr,wc) grid: W staging
// amortized 2x (W logical 200->100MB), barriers per X-byte halved, staging
// per thread per K-step = 2 X-loads + 2 W-loads + 2 uint4 LDS stores.
// Schedule = round-3 proven 1-deep register prefetch, 2 barriers/step
// (ledger: dbuf ✗, async global_load_lds ✗, 2-deep prefetch ✗).
__global__ __launch_bounds__(1024) void gemm_q8(
    const float* __restrict__ X, const float* __restrict__ W,
    unsigned* __restrict__ H32, float* __restrict__ S, int M) {
    __shared__ ushort As[256][32];
    __shared__ ushort Bs[256][32];   // 32 KB total

    const int t    = threadIdx.x;
    const int lane = t & 63;
    const int wave = t >> 6;             // 0..15
    const int wr   = (wave >> 2) * 64;   // 0,64,128,192
    const int wc   = (wave & 3) * 64;    // 0,64,128,192
    const int m0   = blockIdx.x * 256;

    f32x4 acc[4][4] = {};

    const int srow = t >> 2;          // 0..255 (one staged row per thread)
    const int sc8  = (t & 3) * 8;     // float col 0,8,16,24
    const int gr   = m0 + srow;
    const bool inr = gr < M;
    const float* const xp = X + (size_t)gr * FEAT + sc8;
    const float* const wp = W + (size_t)srow * FEAT + sc8;

    const int r  = lane & 15;
    const int kr = (lane >> 4) * 8;

    // prologue: load step 0 (1-deep prefetch)
    f32x4 xv0 = {0.f, 0.f, 0.f, 0.f}, xv1 = {0.f, 0.f, 0.f, 0.f};
    f32x4 wv0, wv1;
    if (inr) { xv0 = *(const f32x4*)xp; xv1 = *(const f32x4*)(xp + 4); }
    wv0 = *(const f32x4*)wp;
    wv1 = *(const f32x4*)(wp + 4);

    for (int k0 = 0; k0 < FEAT; k0 += 32) {
        __syncthreads();   // prev step's ds_reads done; LDS reusable
        {
            uint4 ux = {cvtpk(xv0.x, xv0.y), cvtpk(xv0.z, xv0.w),
                        cvtpk(xv1.x, xv1.y), cvtpk(xv1.z, xv1.w)};
            uint4 uw = {cvtpk(wv0.x, wv0.y), cvtpk(wv0.z, wv0.w),
                        cvtpk(wv1.x, wv1.y), cvtpk(wv1.z, wv1.w)};
            *(uint4*)&As[srow][sc8] = ux;
            *(uint4*)&Bs[srow][sc8] = uw;
        }
        __syncthreads();

        // issue next step's loads now; they drain at the NEXT LDS write
        if (k0 + 32 < FEAT) {
            const int kn = k0 + 32;
            xv0 = {0.f, 0.f, 0.f, 0.f};
            xv1 = {0.f, 0.f, 0.f, 0.f};
            if (inr) { xv0 = *(const f32x4*)(xp + kn); xv1 = *(const f32x4*)(xp + kn + 4); }
            wv0 = *(const f32x4*)(wp + kn);
            wv1 = *(const f32x4*)(wp + kn + 4);
        }

        short8 a[4], b[4];
        #pragma unroll
        for (int i = 0; i < 4; ++i) a[i] = *(const short8*)&As[wr + i * 16 + r][kr];
        #pragma unroll
        for (int j = 0; j < 4; ++j) b[j] = *(const short8*)&Bs[wc + j * 16 + r][kr];
        #pragma unroll
        for (int i = 0; i < 4; ++i)
            #pragma unroll
            for (int j = 0; j < 4; ++j)
                acc[i][j] = __builtin_amdgcn_mfma_f32_16x16x32_bf16(a[i], b[j], acc[i][j], 0, 0, 0);
    }

    // epilogue: C/D mapping col = wc + j*16 + (lane&15), row = wr + i*16 + (lane>>4)*4 + q.
    const int g  = lane >> 4;
    const int cc = lane & 15;
    const int b  = wave & 3;          // 64-col block index (= wc/64)
    #pragma unroll
    for (int i = 0; i < 4; ++i) {
        #pragma unroll
        for (int q = 0; q < 4; ++q) {
            const int row = m0 + wr + i * 16 + g * 4 + q;
            float mx = fmaxf(fmaxf(fabsf(acc[i][0][q]), fabsf(acc[i][1][q])),
                             fmaxf(fabsf(acc[i][2][q]), fabsf(acc[i][3][q])));
            mx = fmaxf(mx, __shfl_xor(mx, 1, 64));
            mx = fmaxf(mx, __shfl_xor(mx, 2, 64));
            mx = fmaxf(mx, __shfl_xor(mx, 4, 64));
            mx = fmaxf(mx, __shfl_xor(mx, 8, 64));
            const float inv = mx > 1e-30f ? 127.0f * __builtin_amdgcn_rcpf(mx) : 0.0f;
            if (row < M) {
                unsigned wdw = 0;
                #pragma unroll
                for (int j = 0; j < 4; ++j) {
                    int u = (int)fmaf(acc[i][j][q], inv, 128.5f);
                    u = u < 0 ? 0 : (u > 255 ? 255 : u);
                    wdw |= (unsigned)u << (8 * j);
                }
                H32[(size_t)row * 64 + b * 16 + cc] = wdw;
                if (cc == 0) S[(size_t)row * 4 + b] = mx * (1.0f / 127.0f);
            }
        }
    }
}

// edge_dst is sorted: rp[n] = first edge with dst >= n; rp[N] = E.
__global__ __launch_bounds__(256) void build_rowptr(
    const int* __restrict__ dst, int* __restrict__ rp, int E, int N) {
    int e = blockIdx.x * 256 + threadIdx.x;
    if (e >= E) return;
    int d    = dst[e];
    int prev = (e == 0) ? -1 : dst[e - 1];
    for (int n = prev + 1; n <= d; ++n) rp[n] = e;
    if (e == E - 1) {
        for (int n = d + 1; n <= N; ++n) rp[n] = E;
    }
}

// SpMM over int8 H (256B rows). 16-lane group per node (4 nodes/wave); lane
// owns 16 bytes (one uint4) of the row. Dual chains = 8 edges in flight/wave.
// Dequant bias-correction: out = sum(vs*u) - 128*sum(vs). NT stores.
// FROZEN: schedule variants (4-deep x2) neutral/worse; column-slicing
// catastrophic (FETCH 228MB -> 1.05GB). Round-0 form = structural floor
// (FETCH at the random-gather limit, ~55% of logical bytes L2/L3-absorbed).
__global__ __launch_bounds__(256) void spmm_q8(
    const uint4* __restrict__ H16, const float* __restrict__ S,
    const int* __restrict__ rp, const int* __restrict__ src,
    const float* __restrict__ val, float* __restrict__ out, int M) {
    const int lane = threadIdx.x & 63;
    const int wave = threadIdx.x >> 6;
    const int li   = lane & 15;          // lane within group
    const int grp  = lane >> 4;          // group 0..3
    const int b    = li >> 2;            // 64-col block
    const int node = blockIdx.x * 16 + wave * 4 + grp;
    if (node >= M) return;
    const int lo = rp[node], hi = rp[node + 1];

    float a0[16], a1[16];                // k = d*4 + j
    #pragma unroll
    for (int k = 0; k < 16; ++k) { a0[k] = 0.f; a1[k] = 0.f; }
    float corr0 = 0.f, corr1 = 0.f;

    for (int e = lo; e < hi; e += 2) {
        const int e1 = e + 1;
        const int c1 = e1 < hi ? e1 : e;
        const int s0 = src[e], s1 = src[c1];
        const float v0 = val[e];
        float v1 = e1 < hi ? val[c1] : 0.f;
        const float vs0 = v0 * S[(size_t)s0 * 4 + b];
        const float vs1 = v1 * S[(size_t)s1 * 4 + b];
        const uint4 p0 = H16[(size_t)s0 * 16 + li];
        const uint4 p1 = H16[(size_t)s1 * 16 + li];
        corr0 += vs0;
        corr1 += vs1;
        const unsigned pd0[4] = {p0.x, p0.y, p0.z, p0.w};
        const unsigned pd1[4] = {p1.x, p1.y, p1.z, p1.w};
        #pragma unroll
        for (int d = 0; d < 4; ++d) {
            #pragma unroll
            for (int j = 0; j < 4; ++j) {
                a0[d * 4 + j] += vs0 * (float)((pd0[d] >> (8 * j)) & 0xffu);
                a1[d * 4 + j] += vs1 * (float)((pd1[d] >> (8 * j)) & 0xffu);
            }
        }
    }

    const float corr = (corr0 + corr1) * 128.0f;
    float* const obase = out + (size_t)node * EMB + b * 64 + (li & 3) * 4;
    #pragma unroll
    for (int j = 0; j < 4; ++j) {
        f32x4 o = {a0[j]      + a1[j]      - corr,
                   a0[4 + j]  + a1[4 + j]  - corr,
                   a0[8 + j]  + a1[8 + j]  - corr,
                   a0[12 + j] + a1[12 + j] - corr};
        __builtin_nontemporal_store(o, (f32x4*)(obase + j * 16));
    }
}

extern "C" void kernel_launch(void* const* d_in, const int* in_sizes, int n_in,
                              void* d_out, int out_size, void* d_ws, size_t ws_size,
                              hipStream_t stream) {
    const float* x    = (const float*)d_in[0];
    const float* w    = (const float*)d_in[1];
    const int*   esrc = (const int*)d_in[2];
    const int*   edst = (const int*)d_in[3];
    const float* eval = (const float*)d_in[4];

    const int M = in_sizes[0] / FEAT;   // 100000
    const int E = in_sizes[2];          // 1600000

    unsigned* Hbuf = (unsigned*)d_ws;                               // [M][64] dwords (int8 rows)
    float*    S    = (float*)((char*)d_ws + (size_t)M * 256);       // [M][4] scales
    int*      rp   = (int*)((char*)S + (size_t)M * 4 * sizeof(float));

    gemm_q8<<<(M + 255) / 256, 1024, 0, stream>>>(x, w, Hbuf, S, M);
    build_rowptr<<<(E + 255) / 256, 256, 0, stream>>>(edst, rp, E, M);
    spmm_q8<<<(M + 15) / 16, 256, 0, stream>>>((const uint4*)Hbuf, S, rp, esrc, eval,
                                               (float*)d_out, M);
}

// Round 8
// 127.284 us; speedup vs baseline: 1.1018x; 1.1018x over previous
//
#include <hip/hip_runtime.h>

#define FEAT 256
#define EMB 256

typedef __attribute__((ext_vector_type(4))) float f32x4;
typedef __attribute__((ext_vector_type(8))) short short8;

// packed fp32x2 -> bf16x2 (RNE) in one instruction
__device__ __forceinline__ unsigned cvtpk(float lo, float hi) {
    unsigned r;
    asm volatile("v_cvt_pk_bf16_f32 %0, %1, %2" : "=v"(r) : "v"(lo), "v"(hi));
    return r;
}

// h = X @ W^T quantized to int8 (biased-u8). H layout: row-major 256B rows,
// within-row byte order [blk(4)][cc(16)][j(4)] so dword (blk*16+cc) holds the
// 4 j-values (cols blk*64 + j*16 + cc) of MFMA lane cc -> single dword store.
// S[row][blk] = per-(row, 64-col block) dequant scale (wave-local absmax).
// Register-prefetch pipeline (PROVEN BEST, round 3 = 127.1us total):
// step k+1's X/W loads issue right after the post-stage barrier and retire
// at step k+1's LDS write -> global latency hides under ds_read + 16 MFMA +
// barrier. FULL LEDGER of attempted gemm variants, all regressed:
//   async global_load_lds B-staging  ✗ (+5us)
//   bf16-W pre-convert (wprep)       ✗ (W is L2-resident; saves nothing)
//   single-barrier LDS double-buffer ✗ (serializes MFMA->vmcnt->write)
//   2-deep A/B register prefetch     ✗ (+24 VGPR live ranges; ~+9us)
//   256-row tile / 1024 threads      ✗ (16-wave barriers, 1.5 blocks/CU)
__global__ __launch_bounds__(512) void gemm_q8(
    const float* __restrict__ X, const float* __restrict__ W,
    unsigned* __restrict__ H32, float* __restrict__ S, int M) {
    __shared__ ushort As[128][32];
    __shared__ ushort Bs[256][32];

    const int t    = threadIdx.x;
    const int lane = t & 63;
    const int wave = t >> 6;
    const int wr   = (wave >> 2) * 64;   // 0 or 64
    const int wc   = (wave & 3) * 64;    // 0,64,128,192
    const int m0   = blockIdx.x * 128;

    f32x4 acc[4][4] = {};

    const int srow = t >> 3;          // 0..63
    const int sc4  = (t & 7) * 4;     // col 0,4,...,28
    const int gr0  = m0 + srow;
    const int gr1  = m0 + srow + 64;
    const float* const xp0 = X + (size_t)gr0 * FEAT + sc4;
    const float* const xp1 = X + (size_t)gr1 * FEAT + sc4;
    const float* const wp  = W + (size_t)srow * FEAT + sc4;

    // prologue: load step 0
    f32x4 xv0 = {0.f, 0.f, 0.f, 0.f}, xv1 = {0.f, 0.f, 0.f, 0.f};
    f32x4 wv[4];
    if (gr0 < M) xv0 = *(const f32x4*)xp0;
    if (gr1 < M) xv1 = *(const f32x4*)xp1;
    #pragma unroll
    for (int j = 0; j < 4; ++j) wv[j] = *(const f32x4*)(wp + (size_t)j * 64 * FEAT);

    for (int k0 = 0; k0 < FEAT; k0 += 32) {
        __syncthreads();   // prev step's ds_reads done; LDS reusable
        {
            uint2 u0 = {cvtpk(xv0.x, xv0.y), cvtpk(xv0.z, xv0.w)};
            uint2 u1 = {cvtpk(xv1.x, xv1.y), cvtpk(xv1.z, xv1.w)};
            *(uint2*)&As[srow][sc4]      = u0;
            *(uint2*)&As[srow + 64][sc4] = u1;
            #pragma unroll
            for (int j = 0; j < 4; ++j) {
                uint2 uw = {cvtpk(wv[j].x, wv[j].y), cvtpk(wv[j].z, wv[j].w)};
                *(uint2*)&Bs[srow + 64 * j][sc4] = uw;
            }
        }
        __syncthreads();

        // issue next step's loads now; they drain at the NEXT LDS write
        if (k0 + 32 < FEAT) {
            const int kn = k0 + 32;
            xv0 = {0.f, 0.f, 0.f, 0.f};
            xv1 = {0.f, 0.f, 0.f, 0.f};
            if (gr0 < M) xv0 = *(const f32x4*)(xp0 + kn);
            if (gr1 < M) xv1 = *(const f32x4*)(xp1 + kn);
            #pragma unroll
            for (int j = 0; j < 4; ++j)
                wv[j] = *(const f32x4*)(wp + (size_t)j * 64 * FEAT + kn);
        }

        const int r  = lane & 15;
        const int kr = (lane >> 4) * 8;
        short8 a[4], b[4];
        #pragma unroll
        for (int i = 0; i < 4; ++i) a[i] = *(const short8*)&As[wr + i * 16 + r][kr];
        #pragma unroll
        for (int j = 0; j < 4; ++j) b[j] = *(const short8*)&Bs[wc + j * 16 + r][kr];
        #pragma unroll
        for (int i = 0; i < 4; ++i)
            #pragma unroll
            for (int j = 0; j < 4; ++j)
                acc[i][j] = __builtin_amdgcn_mfma_f32_16x16x32_bf16(a[i], b[j], acc[i][j], 0, 0, 0);
    }

    // epilogue: C/D mapping col = wc + j*16 + (lane&15), row = wr + i*16 + (lane>>4)*4 + q.
    const int g  = lane >> 4;
    const int cc = lane & 15;
    const int b  = wave & 3;          // 64-col block index (= wc/64)
    #pragma unroll
    for (int i = 0; i < 4; ++i) {
        #pragma unroll
        for (int q = 0; q < 4; ++q) {
            const int row = m0 + wr + i * 16 + g * 4 + q;
            float mx = fmaxf(fmaxf(fabsf(acc[i][0][q]), fabsf(acc[i][1][q])),
                             fmaxf(fabsf(acc[i][2][q]), fabsf(acc[i][3][q])));
            mx = fmaxf(mx, __shfl_xor(mx, 1, 64));
            mx = fmaxf(mx, __shfl_xor(mx, 2, 64));
            mx = fmaxf(mx, __shfl_xor(mx, 4, 64));
            mx = fmaxf(mx, __shfl_xor(mx, 8, 64));
            const float inv = mx > 1e-30f ? 127.0f * __builtin_amdgcn_rcpf(mx) : 0.0f;
            if (row < M) {
                unsigned wdw = 0;
                #pragma unroll
                for (int j = 0; j < 4; ++j) {
                    int u = (int)fmaf(acc[i][j][q], inv, 128.5f);
                    u = u < 0 ? 0 : (u > 255 ? 255 : u);
                    wdw |= (unsigned)u << (8 * j);
                }
                H32[(size_t)row * 64 + b * 16 + cc] = wdw;
                if (cc == 0) S[(size_t)row * 4 + b] = mx * (1.0f / 127.0f);
            }
        }
    }
}

// edge_dst is sorted: rp[n] = first edge with dst >= n; rp[N] = E.
__global__ __launch_bounds__(256) void build_rowptr(
    const int* __restrict__ dst, int* __restrict__ rp, int E, int N) {
    int e = blockIdx.x * 256 + threadIdx.x;
    if (e >= E) return;
    int d    = dst[e];
    int prev = (e == 0) ? -1 : dst[e - 1];
    for (int n = prev + 1; n <= d; ++n) rp[n] = e;
    if (e == E - 1) {
        for (int n = d + 1; n <= N; ++n) rp[n] = E;
    }
}

// SpMM over int8 H (256B rows). 16-lane group per node (4 nodes/wave); lane
// owns 16 bytes (one uint4) of the row. Dual chains = 8 edges in flight/wave.
// Dequant bias-correction: out = sum(vs*u) - 128*sum(vs). NT stores.
// FROZEN at structural floor: FETCH 228MB = random-gather limit (~55% of
// the 410MB logical gather absorbed by L2/L3); schedule variants (4-deep x2)
// neutral/worse; column-slicing catastrophic (FETCH -> 1.05GB from
// line-granularity misses x8 slices). int4 rows would ~18x the quant error.
__global__ __launch_bounds__(256) void spmm_q8(
    const uint4* __restrict__ H16, const float* __restrict__ S,
    const int* __restrict__ rp, const int* __restrict__ src,
    const float* __restrict__ val, float* __restrict__ out, int M) {
    const int lane = threadIdx.x & 63;
    const int wave = threadIdx.x >> 6;
    const int li   = lane & 15;          // lane within group
    const int grp  = lane >> 4;          // group 0..3
    const int b    = li >> 2;            // 64-col block
    const int node = blockIdx.x * 16 + wave * 4 + grp;
    if (node >= M) return;
    const int lo = rp[node], hi = rp[node + 1];

    float a0[16], a1[16];                // k = d*4 + j
    #pragma unroll
    for (int k = 0; k < 16; ++k) { a0[k] = 0.f; a1[k] = 0.f; }
    float corr0 = 0.f, corr1 = 0.f;

    for (int e = lo; e < hi; e += 2) {
        const int e1 = e + 1;
        const int c1 = e1 < hi ? e1 : e;
        const int s0 = src[e], s1 = src[c1];
        const float v0 = val[e];
        float v1 = e1 < hi ? val[c1] : 0.f;
        const float vs0 = v0 * S[(size_t)s0 * 4 + b];
        const float vs1 = v1 * S[(size_t)s1 * 4 + b];
        const uint4 p0 = H16[(size_t)s0 * 16 + li];
        const uint4 p1 = H16[(size_t)s1 * 16 + li];
        corr0 += vs0;
        corr1 += vs1;
        const unsigned pd0[4] = {p0.x, p0.y, p0.z, p0.w};
        const unsigned pd1[4] = {p1.x, p1.y, p1.z, p1.w};
        #pragma unroll
        for (int d = 0; d < 4; ++d) {
            #pragma unroll
            for (int j = 0; j < 4; ++j) {
                a0[d * 4 + j] += vs0 * (float)((pd0[d] >> (8 * j)) & 0xffu);
                a1[d * 4 + j] += vs1 * (float)((pd1[d] >> (8 * j)) & 0xffu);
            }
        }
    }

    const float corr = (corr0 + corr1) * 128.0f;
    float* const obase = out + (size_t)node * EMB + b * 64 + (li & 3) * 4;
    #pragma unroll
    for (int j = 0; j < 4; ++j) {
        f32x4 o = {a0[j]      + a1[j]      - corr,
                   a0[4 + j]  + a1[4 + j]  - corr,
                   a0[8 + j]  + a1[8 + j]  - corr,
                   a0[12 + j] + a1[12 + j] - corr};
        __builtin_nontemporal_store(o, (f32x4*)(obase + j * 16));
    }
}

extern "C" void kernel_launch(void* const* d_in, const int* in_sizes, int n_in,
                              void* d_out, int out_size, void* d_ws, size_t ws_size,
                              hipStream_t stream) {
    const float* x    = (const float*)d_in[0];
    const float* w    = (const float*)d_in[1];
    const int*   esrc = (const int*)d_in[2];
    const int*   edst = (const int*)d_in[3];
    const float* eval = (const float*)d_in[4];

    const int M = in_sizes[0] / FEAT;   // 100000
    const int E = in_sizes[2];          // 1600000

    unsigned* Hbuf = (unsigned*)d_ws;                               // [M][64] dwords (int8 rows)
    float*    S    = (float*)((char*)d_ws + (size_t)M * 256);       // [M][4] scales
    int*      rp   = (int*)((char*)S + (size_t)M * 4 * sizeof(float));

    gemm_q8<<<(M + 127) / 128, 512, 0, stream>>>(x, w, Hbuf, S, M);
    build_rowptr<<<(E + 255) / 256, 256, 0, stream>>>(edst, rp, E, M);
    spmm_q8<<<(M + 15) / 16, 256, 0, stream>>>((const uint4*)Hbuf, S, rp, esrc, eval,
                                               (float*)d_out, M);
}